// Round 10
// baseline (319.215 us; speedup 1.0000x reference)
//
#include <hip/hip_runtime.h>
#include <math.h>

#define HIDD 512
#define NH 8
#define HD 64
#define KCLIP 64
#define LCO 767
#define BB 2
#define SS 768

#define TQ 32            // q-rows per attention block
#define KT 64            // k-tile
#define NT (SS / KT)     // 12 tiles total
#define KS 4             // attention k-split factor
#define TPB (NT / KS)    // 3 tiles per block
#define NROW (BB * NH * SS)   // 12288 (bn,q) rows
#define QPAD 68          // padded row stride for qpk buffer
#define MM (BB * SS)     // 1536 rows in projection GEMMs
#define NPROJ (MM * HIDD)     // 786432 elems per q/k/v tensor

// ---------------------------------------------------------------------------
// K0: prefill idx: 64 everywhere, 0 on pad row 0 / pad col 0 / diagonal.
// ---------------------------------------------------------------------------
__global__ __launch_bounds__(256) void idx_fill_kernel(int* __restrict__ idx)
{
    size_t gid = (size_t)blockIdx.x * 256 + threadIdx.x;
    size_t base = gid * 4;
    int rem = (int)(base % (size_t)(SS * SS));
    int r = rem / SS, c0 = rem % SS;
    int4 v;
    int* vv = (int*)&v;
#pragma unroll
    for (int u = 0; u < 4; ++u) {
        int c = c0 + u;
        vv[u] = (r == 0 || c == 0 || r == c) ? 0 : KCLIP;
    }
    *(int4*)(idx + base) = v;
}

// ---------------------------------------------------------------------------
// K1: relative-position rank indices via 64-NN selection (unchanged).
// ---------------------------------------------------------------------------
__global__ __launch_bounds__(256) void rel_idx_kernel(
    const float* __restrict__ coords, int* __restrict__ idx)
{
    __shared__ float cx[LCO], cy[LCO];
    __shared__ unsigned long long dk[LCO];
    __shared__ unsigned long long lst[LCO];
    __shared__ int hist[256];
    __shared__ int cum[256];
    __shared__ int nsel;
    __shared__ int thrB;

    const int blk = blockIdx.x;
    const int b = blk / LCO;
    const int i = blk % LCO;
    const int t = threadIdx.x;
    const float* cb = coords + (size_t)b * LCO * 2;

    hist[t] = 0;
    if (t == 0) nsel = 0;
    for (int j = t; j < LCO; j += 256) {
        float2 c2 = *(const float2*)(cb + 2 * j);
        cx[j] = c2.x; cy[j] = c2.y;
    }
    __syncthreads();
    const float xi = cx[i], yi = cy[i];
    for (int j = t; j < LCO; j += 256) {
        float dx = xi - cx[j];
        float dy = yi - cy[j];
        float d2 = __fadd_rn(__fmul_rn(dx, dx), __fmul_rn(dy, dy));
        float d = sqrtf(d2);
        dk[j] = ((unsigned long long)__float_as_uint(d) << 32) | (unsigned)j;
        int bkt = (int)(d * 32.0f);
        bkt = bkt > 255 ? 255 : bkt;
        atomicAdd(&hist[bkt], 1);
    }
    __syncthreads();

    cum[t] = hist[t];
    __syncthreads();
    for (int off = 1; off < 256; off <<= 1) {
        int add = (t >= off) ? cum[t - off] : 0;
        __syncthreads();
        cum[t] += add;
        __syncthreads();
    }
    if (cum[t] >= KCLIP && (t == 0 || cum[t - 1] < KCLIP)) thrB = t;
    __syncthreads();
    const int B = thrB;

    const int lane = t & 63;
#pragma unroll
    for (int u = 0; u < 3; ++u) {
        int j = t + u * 256;
        bool sel = false;
        unsigned long long key = 0;
        if (j < LCO) {
            key = dk[j];
            float d = __uint_as_float((unsigned)(key >> 32));
            int bkt = (int)(d * 32.0f);
            bkt = bkt > 255 ? 255 : bkt;
            sel = (bkt <= B);
        }
        unsigned long long m = __ballot(sel);
        int base;
        if (lane == 0) base = atomicAdd(&nsel, __popcll(m));
        base = __shfl(base, 0);
        if (sel) {
            int pfx = __popcll(m & ((1ull << lane) - 1));
            lst[base + pfx] = key;
        }
    }
    __syncthreads();
    const int C = nsel;

    int* ib = idx + (size_t)b * SS * SS;
    for (int c = t; c < C; c += 256) {
        unsigned long long myk = lst[c];
        int cnt = 0;
        for (int c2 = 0; c2 < C; ++c2) cnt += (lst[c2] < myk);
        int j = (int)(myk & 0xffffffffu);
        if (cnt < KCLIP && j > i) {
            ib[(size_t)(i + 1) * SS + (j + 1)] = cnt;
            ib[(size_t)(j + 1) * SS + (i + 1)] = cnt;
        }
    }
}

// ---------------------------------------------------------------------------
// K2a: split-K QKV projection, NON-ATOMIC (unchanged from r8).
// ---------------------------------------------------------------------------
__global__ __launch_bounds__(256) void proj_part_kernel(
    const float* __restrict__ qin, const float* __restrict__ kin, const float* __restrict__ vin,
    const float* __restrict__ Wq, const float* __restrict__ Wk, const float* __restrict__ Wv,
    float* __restrict__ ppart)
{
    const int zc = blockIdx.z;
    const int z = zc >> 2, ksp = zc & 3;
    const float* A = (z == 0) ? qin : (z == 1) ? kin : vin;
    const float* W = (z == 0) ? Wq : (z == 1) ? Wk : Wv;
    const int h = blockIdx.y;
    const int m0 = blockIdx.x * 64;
    const int kbase = ksp * 128;

    __shared__ float As[32][68];   // [k][m]
    __shared__ float Bs[32][64];   // [k][n]

    const int t = threadIdx.x;
    const int tx = t & 15, ty = t >> 4;
    const float* Wh = W + (size_t)h * HIDD * HD;

    float acc[4][4] = {};
    for (int k0i = 0; k0i < 4; ++k0i) {
        const int k0 = kbase + k0i * 32;
#pragma unroll
        for (int u = 0; u < 2; ++u) {
            int i = t + u * 256;
            int row = i >> 3, kc = (i & 7) * 4;
            float4 a4 = *(const float4*)(A + (size_t)(m0 + row) * HIDD + k0 + kc);
            As[kc + 0][row] = a4.x; As[kc + 1][row] = a4.y;
            As[kc + 2][row] = a4.z; As[kc + 3][row] = a4.w;
            int kr = i >> 4, n4 = (i & 15) * 4;
            *(float4*)(&Bs[kr][n4]) = *(const float4*)(Wh + (size_t)(k0 + kr) * HD + n4);
        }
        __syncthreads();
#pragma unroll
        for (int kk = 0; kk < 32; ++kk) {
            float4 a4 = *(const float4*)(&As[kk][ty * 4]);
            float4 b4 = *(const float4*)(&Bs[kk][tx * 4]);
            float a_[4] = {a4.x, a4.y, a4.z, a4.w};
            float b_[4] = {b4.x, b4.y, b4.z, b4.w};
#pragma unroll
            for (int r = 0; r < 4; ++r)
#pragma unroll
                for (int c = 0; c < 4; ++c) acc[r][c] += a_[r] * b_[c];
        }
        __syncthreads();
    }
    float* pp = ppart + ((size_t)(z * 4 + ksp) * MM + m0) * HIDD;
#pragma unroll
    for (int r = 0; r < 4; ++r) {
        int row = ty * 4 + r;
        *(float4*)(pp + (size_t)row * HIDD + h * HD + tx * 4) = *(float4*)(acc[r]);
    }
}

// ---------------------------------------------------------------------------
// K2b: combine 4 K-slice partials + bias -> q/v (direct) and kT (LDS
// transpose). (unchanged from r8)
// ---------------------------------------------------------------------------
__global__ __launch_bounds__(256) void proj_combine_kernel(
    const float* __restrict__ ppart,
    const float* __restrict__ bq, const float* __restrict__ bk, const float* __restrict__ bv,
    float* __restrict__ qo, float* __restrict__ kTo, float* __restrict__ vo)
{
    const int z = blockIdx.z, h = blockIdx.y, m0 = blockIdx.x * 64;
    const int t = threadIdx.x;
    const float* bias = (z == 0) ? bq : (z == 1) ? bk : bv;
    const int bIdx = m0 / SS, sbase = m0 % SS;
    __shared__ float TsT[64][65];

#pragma unroll
    for (int i = 0; i < 4; ++i) {
        int f = t + i * 256;
        int row = f >> 4, col4 = (f & 15) * 4;
        const float* p0 = ppart + ((size_t)(z * 4) * MM + m0 + row) * HIDD + h * HD + col4;
        float4 s0 = *(const float4*)(p0);
        float4 s1 = *(const float4*)(p0 + (size_t)MM * HIDD);
        float4 s2 = *(const float4*)(p0 + (size_t)2 * MM * HIDD);
        float4 s3 = *(const float4*)(p0 + (size_t)3 * MM * HIDD);
        float4 bb = *(const float4*)(bias + h * HD + col4);
        float4 r;
        r.x = s0.x + s1.x + s2.x + s3.x + bb.x;
        r.y = s0.y + s1.y + s2.y + s3.y + bb.y;
        r.z = s0.z + s1.z + s2.z + s3.z + bb.z;
        r.w = s0.w + s1.w + s2.w + s3.w + bb.w;
        if (z != 1) {
            float* O = (z == 0) ? qo : vo;
            *(float4*)(O + ((size_t)(bIdx * NH + h) * SS + sbase + row) * HD + col4) = r;
        } else {
            TsT[col4 + 0][row] = r.x;
            TsT[col4 + 1][row] = r.y;
            TsT[col4 + 2][row] = r.z;
            TsT[col4 + 3][row] = r.w;
        }
    }
    if (z == 1) {
        __syncthreads();
        int d = t >> 2, s0 = (t & 3) * 16;
        float* krow = kTo + ((size_t)(bIdx * NH + h) * HD + d) * SS + sbase;
#pragma unroll
        for (int i = 0; i < 4; ++i) {
            *(float4*)(krow + s0 + 4 * i) = *(const float4*)(&TsT[d][s0 + 4 * i]);
        }
    }
}

// ---------------------------------------------------------------------------
// K2c: qpk[row][c] = q_row . pe_k[c]. (unchanged)
// ---------------------------------------------------------------------------
__global__ __launch_bounds__(256) void qpk_kernel(
    const float* __restrict__ q, const float* __restrict__ pe_k, float* __restrict__ qpkg)
{
    __shared__ float qs[16][68];
    __shared__ float pk[65][68];
    const int t = threadIdx.x;
    const int q0 = blockIdx.x * 16;
    const int bn = blockIdx.y;
    const float* qbase = q + ((size_t)bn * SS + q0) * HD;
    {
        int row = t >> 4, d4 = (t & 15) * 4;
        *(float4*)(&qs[row][d4]) = *(const float4*)(qbase + (size_t)row * HD + d4);
    }
    for (int i = t; i < 65 * 16; i += 256) {
        int c = i >> 4, d4 = (i & 15) * 4;
        *(float4*)(&pk[c][d4]) = *(const float4*)(pe_k + (size_t)c * HD + d4);
    }
    __syncthreads();
    const int qr = t >> 4, cg = t & 15;
    float* orow = qpkg + ((size_t)bn * SS + q0 + qr) * QPAD;
    for (int c = cg; c <= KCLIP; c += 16) {
        float acc = 0.f;
#pragma unroll
        for (int d4 = 0; d4 < HD; d4 += 4) {
            float4 qv = *(const float4*)(&qs[qr][d4]);
            float4 pv = *(const float4*)(&pk[c][d4]);
            acc += qv.x * pv.x + qv.y * pv.y + qv.z * pv.z + qv.w * pv.w;
        }
        orow[c] = acc;
    }
}

// ---------------------------------------------------------------------------
// K3a: split-K attention partial — DIRECT-GLOBAL K/V (no kv LDS), barrier-free
// main loop. K/V panels (192 KB per bn) are L2-resident and reused by 24
// blocks; attQ/wbuf rows are WAVE-LOCAL (qh = t>>4 spans one wave quarter),
// so no __syncthreads() needed between QK and PV. LDS 33.4 KB -> 4 blocks/CU.
// ---------------------------------------------------------------------------
__global__ __launch_bounds__(256) void attn_part_kernel(
    const float* __restrict__ q, const float* __restrict__ kT,
    const float* __restrict__ vb, const int* __restrict__ idx,
    const float* __restrict__ qpkg,
    float* __restrict__ o1p, float* __restrict__ pspart, float* __restrict__ wbpart)
{
    __shared__ float qsT[HD][TQ];        // 8K   [d][q]
    __shared__ float attQ[TQ][68];       // 8.7K (wave-local rows)
    __shared__ float qpkS[TQ][QPAD];     // 8.7K
    __shared__ float wbuf[TQ][KCLIP];    // 8K   (wave-local rows in main loop)

    const int t = threadIdx.x;
    const int bn = blockIdx.y;
    const int b = bn >> 3;
    const int q0 = blockIdx.x * TQ;
    const int ks = blockIdx.z;

    const int qh = t >> 4;     // owns q rows {2qh, 2qh+1}
    const int kg = t & 15;     // QK: 4 k-cols; PV: 4 d-cols

    const float* qbase = q + ((size_t)bn * SS + q0) * HD;
    for (int i = t; i < TQ * 16; i += 256) {
        int r = i >> 4, dx = (i & 15) * 4;
        float4 v4 = *(const float4*)(qbase + (size_t)r * HD + dx);
        qsT[dx + 0][r] = v4.x; qsT[dx + 1][r] = v4.y;
        qsT[dx + 2][r] = v4.z; qsT[dx + 3][r] = v4.w;
    }
    for (int i = t; i < TQ * 17; i += 256) {
        int r = i / 17, c4 = (i % 17) * 4;
        *(float4*)(&qpkS[r][c4]) = *(const float4*)(qpkg + ((size_t)bn * SS + q0 + r) * QPAD + c4);
    }
    for (int i = t; i < TQ * KCLIP; i += 256) ((float*)wbuf)[i] = 0.f;
    __syncthreads();

    const float* kTbn = kT + (size_t)bn * HD * SS;
    const float* vbn = vb + (size_t)bn * SS * HD;
    const int* ib = idx + (size_t)b * SS * SS;

    float out1[2][4] = {};
    float psum[2] = {0.f, 0.f};

    for (int t0 = 0; t0 < TPB; ++t0) {
        const int k0 = (ks * TPB + t0) * KT;

        // QK direct from global kT (column-walk, 16 lanes -> 256B/row, L2-hit)
        float acc[2][4] = {};
        const float* kp = kTbn + k0 + 4 * kg;
#pragma unroll 16
        for (int d = 0; d < HD; ++d) {
            float q0v = qsT[d][2 * qh];
            float q1v = qsT[d][2 * qh + 1];
            float4 k4 = *(const float4*)(kp + (size_t)d * SS);
            acc[0][0] += q0v * k4.x; acc[0][1] += q0v * k4.y;
            acc[0][2] += q0v * k4.z; acc[0][3] += q0v * k4.w;
            acc[1][0] += q1v * k4.x; acc[1][1] += q1v * k4.y;
            acc[1][2] += q1v * k4.z; acc[1][3] += q1v * k4.w;
        }
#pragma unroll
        for (int e = 0; e < 2; ++e) {
            int qq = 2 * qh + e;
            int4 iv = *(const int4*)(ib + (size_t)(q0 + qq) * SS + k0 + 4 * kg);
            float p0 = __expf((acc[e][0] + qpkS[qq][iv.x]) * 0.125f);
            float p1 = __expf((acc[e][1] + qpkS[qq][iv.y]) * 0.125f);
            float p2 = __expf((acc[e][2] + qpkS[qq][iv.z]) * 0.125f);
            float p3 = __expf((acc[e][3] + qpkS[qq][iv.w]) * 0.125f);
            float4 pv4; pv4.x = p0; pv4.y = p1; pv4.z = p2; pv4.w = p3;
            *(float4*)(&attQ[qq][4 * kg]) = pv4;
            if (iv.x < KCLIP) atomicAdd(&wbuf[qq][iv.x], p0);
            if (iv.y < KCLIP) atomicAdd(&wbuf[qq][iv.y], p1);
            if (iv.z < KCLIP) atomicAdd(&wbuf[qq][iv.z], p2);
            if (iv.w < KCLIP) atomicAdd(&wbuf[qq][iv.w], p3);
            psum[e] += p0 + p1 + p2 + p3;
        }
        // no barrier: attQ rows 2qh,2qh+1 are produced and consumed by this wave

        // PV direct from global v (row-walk, 16 lanes -> 256B/row, L2-hit)
#pragma unroll 8
        for (int kk = 0; kk < KT; kk += 2) {
            float2 a0 = *(const float2*)(&attQ[2 * qh][kk]);
            float2 a1 = *(const float2*)(&attQ[2 * qh + 1][kk]);
            float4 v0 = *(const float4*)(vbn + (size_t)(k0 + kk) * HD + 4 * kg);
            float4 v1 = *(const float4*)(vbn + (size_t)(k0 + kk + 1) * HD + 4 * kg);
            out1[0][0] += a0.x * v0.x; out1[0][1] += a0.x * v0.y;
            out1[0][2] += a0.x * v0.z; out1[0][3] += a0.x * v0.w;
            out1[1][0] += a1.x * v0.x; out1[1][1] += a1.x * v0.y;
            out1[1][2] += a1.x * v0.z; out1[1][3] += a1.x * v0.w;
            out1[0][0] += a0.y * v1.x; out1[0][1] += a0.y * v1.y;
            out1[0][2] += a0.y * v1.z; out1[0][3] += a0.y * v1.w;
            out1[1][0] += a1.y * v1.x; out1[1][1] += a1.y * v1.y;
            out1[1][2] += a1.y * v1.z; out1[1][3] += a1.y * v1.w;
        }
        // no barrier: next tile's attQ writes are by this same wave
    }

#pragma unroll
    for (int off = 8; off; off >>= 1) {
        psum[0] += __shfl_xor(psum[0], off);
        psum[1] += __shfl_xor(psum[1], off);
    }
    const size_t rbase = (size_t)ks * NROW + (size_t)bn * SS + q0;
    if (kg == 0) {
        pspart[rbase + 2 * qh] = psum[0];
        pspart[rbase + 2 * qh + 1] = psum[1];
    }
#pragma unroll
    for (int e = 0; e < 2; ++e) {
        int qq = 2 * qh + e;
        *(float4*)(o1p + (rbase + qq) * HD + 4 * kg) = *(float4*)(out1[e]);
    }
    __syncthreads();   // wbuf copy-out crosses waves
    for (int i = t; i < TQ * KCLIP / 4; i += 256) {
        int r = i >> 4, c4 = (i & 15) * 4;
        *(float4*)(wbpart + (rbase + r) * KCLIP + c4) = *(const float4*)(&wbuf[r][c4]);
    }
}

// ---------------------------------------------------------------------------
// K3b: combine partials -> heads. (unchanged)
// ---------------------------------------------------------------------------
__global__ __launch_bounds__(256) void attn_combine_kernel(
    const float* __restrict__ o1p, const float* __restrict__ pspart,
    const float* __restrict__ wbpart, const float* __restrict__ pe_v,
    float* __restrict__ heads)
{
    __shared__ float wl[4][66];
    const int t = threadIdx.x;
    const int rt = t >> 6, d = t & 63;
    const int row = blockIdx.x * 4 + rt;
    const int bn = row / SS, qq = row % SS;
    const int b = bn >> 3, n = bn & 7;

    float w = 0.f, rsum = 0.f, o = 0.f;
#pragma unroll
    for (int ks = 0; ks < KS; ++ks) {
        w += wbpart[((size_t)ks * NROW + row) * KCLIP + d];
        rsum += pspart[(size_t)ks * NROW + row];
        o += o1p[((size_t)ks * NROW + row) * HD + d];
    }
    wl[rt][d] = w;
    __syncthreads();

    const float pv64 = pe_v[KCLIP * HD + d];
    float acc = o;
#pragma unroll 8
    for (int c = 0; c < KCLIP; ++c)
        acc += wl[rt][c] * (pe_v[c * HD + d] - pv64);
    heads[((size_t)b * SS + qq) * HIDD + n * HD + d] = acc / rsum + pv64;
}

// ---------------------------------------------------------------------------
// K5: fc: out = heads @ fc_W^T + fc_b. (unchanged)
// ---------------------------------------------------------------------------
__global__ __launch_bounds__(256) void fc_kernel(
    const float* __restrict__ heads, const float* __restrict__ fcW,
    const float* __restrict__ fcb, float* __restrict__ out)
{
    const int m0 = blockIdx.x * 32;
    const int n0 = blockIdx.y * 64;

    __shared__ float As[32][36];
    __shared__ float Bs[32][64];

    const int t = threadIdx.x;
    const int ty = t >> 4;
    const int tx = t & 15;

    float acc[2][4] = {};
    for (int k0 = 0; k0 < HIDD; k0 += 32) {
        {
            int row = t >> 3, kc = (t & 7) * 4;
            float4 a4 = *(const float4*)(heads + (size_t)(m0 + row) * HIDD + k0 + kc);
            As[kc + 0][row] = a4.x; As[kc + 1][row] = a4.y;
            As[kc + 2][row] = a4.z; As[kc + 3][row] = a4.w;
        }
#pragma unroll
        for (int u = 0; u < 2; ++u) {
            int i = t + u * 256;
            int nl = i >> 3, kl = (i & 7) * 4;
            float4 bw = *(const float4*)(fcW + (size_t)(n0 + nl) * HIDD + k0 + kl);
            Bs[kl + 0][nl] = bw.x; Bs[kl + 1][nl] = bw.y;
            Bs[kl + 2][nl] = bw.z; Bs[kl + 3][nl] = bw.w;
        }
        __syncthreads();
#pragma unroll
        for (int kk = 0; kk < 32; ++kk) {
            float a0 = As[kk][2 * ty];
            float a1 = As[kk][2 * ty + 1];
            float4 b4 = *(const float4*)(&Bs[kk][4 * tx]);
            acc[0][0] += a0 * b4.x; acc[0][1] += a0 * b4.y;
            acc[0][2] += a0 * b4.z; acc[0][3] += a0 * b4.w;
            acc[1][0] += a1 * b4.x; acc[1][1] += a1 * b4.y;
            acc[1][2] += a1 * b4.z; acc[1][3] += a1 * b4.w;
        }
        __syncthreads();
    }
    float4 bb = *(const float4*)(fcb + n0 + 4 * tx);
#pragma unroll
    for (int e = 0; e < 2; ++e) {
        float4 r4;
        r4.x = acc[e][0] + bb.x; r4.y = acc[e][1] + bb.y;
        r4.z = acc[e][2] + bb.z; r4.w = acc[e][3] + bb.w;
        *(float4*)(out + (size_t)(m0 + 2 * ty + e) * HIDD + n0 + 4 * tx) = r4;
    }
}

// ---------------------------------------------------------------------------
extern "C" void kernel_launch(void* const* d_in, const int* in_sizes, int n_in,
                              void* d_out, int out_size, void* d_ws, size_t ws_size,
                              hipStream_t stream)
{
    (void)in_sizes; (void)n_in; (void)out_size; (void)ws_size;
    const float* query  = (const float*)d_in[0];
    const float* key_   = (const float*)d_in[1];
    const float* value  = (const float*)d_in[2];
    const float* coords = (const float*)d_in[3];
    const float* Wq = (const float*)d_in[4];
    const float* bq = (const float*)d_in[5];
    const float* Wk = (const float*)d_in[6];
    const float* bk = (const float*)d_in[7];
    const float* Wv = (const float*)d_in[8];
    const float* bv = (const float*)d_in[9];
    const float* pe_k = (const float*)d_in[10];
    const float* pe_v = (const float*)d_in[11];
    const float* fcW  = (const float*)d_in[12];
    const float* fcb  = (const float*)d_in[13];
    float* out = (float*)d_out;

    char* ws = (char*)d_ws;
    size_t off = 0;
    auto alloc = [&](size_t bytes) -> void* {
        void* p = ws + off;
        off += (bytes + 255) & ~(size_t)255;
        return p;
    };
    int*   idx    = (int*)  alloc((size_t)BB * SS * SS * sizeof(int));       // 4.7 MB
    float* qb     = (float*)alloc((size_t)NPROJ * sizeof(float));            // 3 MB
    float* kTb    = (float*)alloc((size_t)NPROJ * sizeof(float));            // 3 MB
    float* vb     = (float*)alloc((size_t)NPROJ * sizeof(float));            // 3 MB
    float* headb  = (float*)alloc((size_t)BB * SS * HIDD * sizeof(float));   // 3 MB
    float* qpkg   = (float*)alloc((size_t)NROW * QPAD * sizeof(float));      // 3.3 MB

    // union region: proj partials (37.7 MB) alias the attention partials
    // (o1p 12.6 + pspart 0.2 + wbpart 12.6 = 25.4 MB). proj partials are
    // fully consumed by proj_combine before attn_part writes o1p/ps/wb.
    const size_t o1p_b = (size_t)KS * NROW * HD * sizeof(float);
    const size_t ps_b  = ((size_t)KS * NROW * sizeof(float) + 255) & ~(size_t)255;
    const size_t pp_b  = (size_t)3 * 4 * MM * HIDD * sizeof(float);
    char* uni = (char*)alloc(pp_b);
    float* ppart  = (float*)uni;
    float* o1p    = (float*)uni;
    float* pspart = (float*)(uni + ((o1p_b + 255) & ~(size_t)255));
    float* wbpart = (float*)(uni + ((o1p_b + 255) & ~(size_t)255) + ps_b);

    idx_fill_kernel<<<(BB * SS * SS) / (256 * 4), 256, 0, stream>>>(idx);

    rel_idx_kernel<<<BB * LCO, 256, 0, stream>>>(coords, idx);

    proj_part_kernel<<<dim3(MM / 64, NH, 12), 256, 0, stream>>>(
        query, key_, value, Wq, Wk, Wv, ppart);

    proj_combine_kernel<<<dim3(MM / 64, NH, 3), 256, 0, stream>>>(
        ppart, bq, bk, bv, qb, kTb, vb);

    qpk_kernel<<<dim3(SS / 16, BB * NH), 256, 0, stream>>>(qb, pe_k, qpkg);

    attn_part_kernel<<<dim3(SS / TQ, BB * NH, KS), 256, 0, stream>>>(
        qb, kTb, vb, idx, qpkg, o1p, pspart, wbpart);

    attn_combine_kernel<<<NROW / 4, 256, 0, stream>>>(o1p, pspart, wbpart, pe_v, headb);

    fc_kernel<<<dim3(MM / 32, HIDD / 64), 256, 0, stream>>>(headb, fcW, fcb, out);
}

// Round 11
// 244.303 us; speedup vs baseline: 1.3066x; 1.3066x over previous
//
#include <hip/hip_runtime.h>
#include <math.h>

#define HIDD 512
#define NH 8
#define HD 64
#define KCLIP 64
#define LCO 767
#define BB 2
#define SS 768

#define TQ 32            // q-rows per attention block
#define KT 64            // k-tile
#define NT (SS / KT)     // 12 tiles total
#define KS 4             // attention k-split factor
#define TPB (NT / KS)    // 3 tiles per block
#define NROW (BB * NH * SS)   // 12288 (bn,q) rows
#define QPAD 68          // padded row stride for qpk buffer
#define MM (BB * SS)     // 1536 rows in projection GEMMs
#define NPROJ (MM * HIDD)     // 786432 elems per q/k/v tensor

// ---------------------------------------------------------------------------
// K0: prefill idx: 64 everywhere, 0 on pad row 0 / pad col 0 / diagonal.
// ---------------------------------------------------------------------------
__global__ __launch_bounds__(256) void idx_fill_kernel(int* __restrict__ idx)
{
    size_t gid = (size_t)blockIdx.x * 256 + threadIdx.x;
    size_t base = gid * 4;
    int rem = (int)(base % (size_t)(SS * SS));
    int r = rem / SS, c0 = rem % SS;
    int4 v;
    int* vv = (int*)&v;
#pragma unroll
    for (int u = 0; u < 4; ++u) {
        int c = c0 + u;
        vv[u] = (r == 0 || c == 0 || r == c) ? 0 : KCLIP;
    }
    *(int4*)(idx + base) = v;
}

// ---------------------------------------------------------------------------
// K1: relative-position rank indices via 64-NN selection (unchanged).
// ---------------------------------------------------------------------------
__global__ __launch_bounds__(256) void rel_idx_kernel(
    const float* __restrict__ coords, int* __restrict__ idx)
{
    __shared__ float cx[LCO], cy[LCO];
    __shared__ unsigned long long dk[LCO];
    __shared__ unsigned long long lst[LCO];
    __shared__ int hist[256];
    __shared__ int cum[256];
    __shared__ int nsel;
    __shared__ int thrB;

    const int blk = blockIdx.x;
    const int b = blk / LCO;
    const int i = blk % LCO;
    const int t = threadIdx.x;
    const float* cb = coords + (size_t)b * LCO * 2;

    hist[t] = 0;
    if (t == 0) nsel = 0;
    for (int j = t; j < LCO; j += 256) {
        float2 c2 = *(const float2*)(cb + 2 * j);
        cx[j] = c2.x; cy[j] = c2.y;
    }
    __syncthreads();
    const float xi = cx[i], yi = cy[i];
    for (int j = t; j < LCO; j += 256) {
        float dx = xi - cx[j];
        float dy = yi - cy[j];
        float d2 = __fadd_rn(__fmul_rn(dx, dx), __fmul_rn(dy, dy));
        float d = sqrtf(d2);
        dk[j] = ((unsigned long long)__float_as_uint(d) << 32) | (unsigned)j;
        int bkt = (int)(d * 32.0f);
        bkt = bkt > 255 ? 255 : bkt;
        atomicAdd(&hist[bkt], 1);
    }
    __syncthreads();

    cum[t] = hist[t];
    __syncthreads();
    for (int off = 1; off < 256; off <<= 1) {
        int add = (t >= off) ? cum[t - off] : 0;
        __syncthreads();
        cum[t] += add;
        __syncthreads();
    }
    if (cum[t] >= KCLIP && (t == 0 || cum[t - 1] < KCLIP)) thrB = t;
    __syncthreads();
    const int B = thrB;

    const int lane = t & 63;
#pragma unroll
    for (int u = 0; u < 3; ++u) {
        int j = t + u * 256;
        bool sel = false;
        unsigned long long key = 0;
        if (j < LCO) {
            key = dk[j];
            float d = __uint_as_float((unsigned)(key >> 32));
            int bkt = (int)(d * 32.0f);
            bkt = bkt > 255 ? 255 : bkt;
            sel = (bkt <= B);
        }
        unsigned long long m = __ballot(sel);
        int base;
        if (lane == 0) base = atomicAdd(&nsel, __popcll(m));
        base = __shfl(base, 0);
        if (sel) {
            int pfx = __popcll(m & ((1ull << lane) - 1));
            lst[base + pfx] = key;
        }
    }
    __syncthreads();
    const int C = nsel;

    int* ib = idx + (size_t)b * SS * SS;
    for (int c = t; c < C; c += 256) {
        unsigned long long myk = lst[c];
        int cnt = 0;
        for (int c2 = 0; c2 < C; ++c2) cnt += (lst[c2] < myk);
        int j = (int)(myk & 0xffffffffu);
        if (cnt < KCLIP && j > i) {
            ib[(size_t)(i + 1) * SS + (j + 1)] = cnt;
            ib[(size_t)(j + 1) * SS + (i + 1)] = cnt;
        }
    }
}

// ---------------------------------------------------------------------------
// K2a: split-K QKV projection, NON-ATOMIC (unchanged from r8).
// ---------------------------------------------------------------------------
__global__ __launch_bounds__(256) void proj_part_kernel(
    const float* __restrict__ qin, const float* __restrict__ kin, const float* __restrict__ vin,
    const float* __restrict__ Wq, const float* __restrict__ Wk, const float* __restrict__ Wv,
    float* __restrict__ ppart)
{
    const int zc = blockIdx.z;
    const int z = zc >> 2, ksp = zc & 3;
    const float* A = (z == 0) ? qin : (z == 1) ? kin : vin;
    const float* W = (z == 0) ? Wq : (z == 1) ? Wk : Wv;
    const int h = blockIdx.y;
    const int m0 = blockIdx.x * 64;
    const int kbase = ksp * 128;

    __shared__ float As[32][68];   // [k][m]
    __shared__ float Bs[32][64];   // [k][n]

    const int t = threadIdx.x;
    const int tx = t & 15, ty = t >> 4;
    const float* Wh = W + (size_t)h * HIDD * HD;

    float acc[4][4] = {};
    for (int k0i = 0; k0i < 4; ++k0i) {
        const int k0 = kbase + k0i * 32;
#pragma unroll
        for (int u = 0; u < 2; ++u) {
            int i = t + u * 256;
            int row = i >> 3, kc = (i & 7) * 4;
            float4 a4 = *(const float4*)(A + (size_t)(m0 + row) * HIDD + k0 + kc);
            As[kc + 0][row] = a4.x; As[kc + 1][row] = a4.y;
            As[kc + 2][row] = a4.z; As[kc + 3][row] = a4.w;
            int kr = i >> 4, n4 = (i & 15) * 4;
            *(float4*)(&Bs[kr][n4]) = *(const float4*)(Wh + (size_t)(k0 + kr) * HD + n4);
        }
        __syncthreads();
#pragma unroll
        for (int kk = 0; kk < 32; ++kk) {
            float4 a4 = *(const float4*)(&As[kk][ty * 4]);
            float4 b4 = *(const float4*)(&Bs[kk][tx * 4]);
            float a_[4] = {a4.x, a4.y, a4.z, a4.w};
            float b_[4] = {b4.x, b4.y, b4.z, b4.w};
#pragma unroll
            for (int r = 0; r < 4; ++r)
#pragma unroll
                for (int c = 0; c < 4; ++c) acc[r][c] += a_[r] * b_[c];
        }
        __syncthreads();
    }
    float* pp = ppart + ((size_t)(z * 4 + ksp) * MM + m0) * HIDD;
#pragma unroll
    for (int r = 0; r < 4; ++r) {
        int row = ty * 4 + r;
        *(float4*)(pp + (size_t)row * HIDD + h * HD + tx * 4) = *(float4*)(acc[r]);
    }
}

// ---------------------------------------------------------------------------
// K2b: combine 4 K-slice partials + bias -> q/v (direct) and kT (LDS
// transpose). (unchanged from r8)
// ---------------------------------------------------------------------------
__global__ __launch_bounds__(256) void proj_combine_kernel(
    const float* __restrict__ ppart,
    const float* __restrict__ bq, const float* __restrict__ bk, const float* __restrict__ bv,
    float* __restrict__ qo, float* __restrict__ kTo, float* __restrict__ vo)
{
    const int z = blockIdx.z, h = blockIdx.y, m0 = blockIdx.x * 64;
    const int t = threadIdx.x;
    const float* bias = (z == 0) ? bq : (z == 1) ? bk : bv;
    const int bIdx = m0 / SS, sbase = m0 % SS;
    __shared__ float TsT[64][65];

#pragma unroll
    for (int i = 0; i < 4; ++i) {
        int f = t + i * 256;
        int row = f >> 4, col4 = (f & 15) * 4;
        const float* p0 = ppart + ((size_t)(z * 4) * MM + m0 + row) * HIDD + h * HD + col4;
        float4 s0 = *(const float4*)(p0);
        float4 s1 = *(const float4*)(p0 + (size_t)MM * HIDD);
        float4 s2 = *(const float4*)(p0 + (size_t)2 * MM * HIDD);
        float4 s3 = *(const float4*)(p0 + (size_t)3 * MM * HIDD);
        float4 bb = *(const float4*)(bias + h * HD + col4);
        float4 r;
        r.x = s0.x + s1.x + s2.x + s3.x + bb.x;
        r.y = s0.y + s1.y + s2.y + s3.y + bb.y;
        r.z = s0.z + s1.z + s2.z + s3.z + bb.z;
        r.w = s0.w + s1.w + s2.w + s3.w + bb.w;
        if (z != 1) {
            float* O = (z == 0) ? qo : vo;
            *(float4*)(O + ((size_t)(bIdx * NH + h) * SS + sbase + row) * HD + col4) = r;
        } else {
            TsT[col4 + 0][row] = r.x;
            TsT[col4 + 1][row] = r.y;
            TsT[col4 + 2][row] = r.z;
            TsT[col4 + 3][row] = r.w;
        }
    }
    if (z == 1) {
        __syncthreads();
        int d = t >> 2, s0 = (t & 3) * 16;
        float* krow = kTo + ((size_t)(bIdx * NH + h) * HD + d) * SS + sbase;
#pragma unroll
        for (int i = 0; i < 4; ++i) {
            *(float4*)(krow + s0 + 4 * i) = *(const float4*)(&TsT[d][s0 + 4 * i]);
        }
    }
}

// ---------------------------------------------------------------------------
// K2c: qpk[row][c] = q_row . pe_k[c]. (unchanged)
// ---------------------------------------------------------------------------
__global__ __launch_bounds__(256) void qpk_kernel(
    const float* __restrict__ q, const float* __restrict__ pe_k, float* __restrict__ qpkg)
{
    __shared__ float qs[16][68];
    __shared__ float pk[65][68];
    const int t = threadIdx.x;
    const int q0 = blockIdx.x * 16;
    const int bn = blockIdx.y;
    const float* qbase = q + ((size_t)bn * SS + q0) * HD;
    {
        int row = t >> 4, d4 = (t & 15) * 4;
        *(float4*)(&qs[row][d4]) = *(const float4*)(qbase + (size_t)row * HD + d4);
    }
    for (int i = t; i < 65 * 16; i += 256) {
        int c = i >> 4, d4 = (i & 15) * 4;
        *(float4*)(&pk[c][d4]) = *(const float4*)(pe_k + (size_t)c * HD + d4);
    }
    __syncthreads();
    const int qr = t >> 4, cg = t & 15;
    float* orow = qpkg + ((size_t)bn * SS + q0 + qr) * QPAD;
    for (int c = cg; c <= KCLIP; c += 16) {
        float acc = 0.f;
#pragma unroll
        for (int d4 = 0; d4 < HD; d4 += 4) {
            float4 qv = *(const float4*)(&qs[qr][d4]);
            float4 pv = *(const float4*)(&pk[c][d4]);
            acc += qv.x * pv.x + qv.y * pv.y + qv.z * pv.z + qv.w * pv.w;
        }
        orow[c] = acc;
    }
}

// ---------------------------------------------------------------------------
// K3a: split-K attention partial — r8 LDS-staged structure, but K and V get
// SEPARATE LDS buffers staged together: 2 barriers/tile instead of 4.
// QK->PV needs no barrier (attQ/wbuf rows are wave-local: wave w owns q rows
// 8w..8w+7). LDS 65.4 KB -> 2 blocks/CU (~8 waves, same as r8's measured avg).
// ---------------------------------------------------------------------------
__global__ __launch_bounds__(256) void attn_part_kernel(
    const float* __restrict__ q, const float* __restrict__ kT,
    const float* __restrict__ vb, const int* __restrict__ idx,
    const float* __restrict__ qpkg,
    float* __restrict__ o1p, float* __restrict__ pspart, float* __restrict__ wbpart)
{
    __shared__ float qsT[HD][TQ];        // 8K   [d][q]
    __shared__ float kA[KT][HD];         // 16K  K tile [d][k]
    __shared__ float vA[KT][HD];         // 16K  V tile [k][d]
    __shared__ float attQ[TQ][68];       // 8.7K (wave-local rows)
    __shared__ float qpkS[TQ][QPAD];     // 8.7K
    __shared__ float wbuf[TQ][KCLIP];    // 8K   (wave-local rows)

    const int t = threadIdx.x;
    const int bn = blockIdx.y;
    const int b = bn >> 3;
    const int q0 = blockIdx.x * TQ;
    const int ks = blockIdx.z;

    const int qh = t >> 4;     // owns q rows {2qh, 2qh+1}
    const int kg = t & 15;     // QK: 4 k-cols; PV: 4 d-cols

    const float* qbase = q + ((size_t)bn * SS + q0) * HD;
    for (int i = t; i < TQ * 16; i += 256) {
        int r = i >> 4, dx = (i & 15) * 4;
        float4 v4 = *(const float4*)(qbase + (size_t)r * HD + dx);
        qsT[dx + 0][r] = v4.x; qsT[dx + 1][r] = v4.y;
        qsT[dx + 2][r] = v4.z; qsT[dx + 3][r] = v4.w;
    }
    for (int i = t; i < TQ * 17; i += 256) {
        int r = i / 17, c4 = (i % 17) * 4;
        *(float4*)(&qpkS[r][c4]) = *(const float4*)(qpkg + ((size_t)bn * SS + q0 + r) * QPAD + c4);
    }
    for (int i = t; i < TQ * KCLIP; i += 256) ((float*)wbuf)[i] = 0.f;
    __syncthreads();

    const float* kTbn = kT + (size_t)bn * HD * SS;
    const float* vbn = vb + (size_t)bn * SS * HD;
    const int* ib = idx + (size_t)b * SS * SS;

    float out1[2][4] = {};
    float psum[2] = {0.f, 0.f};

    for (int t0 = 0; t0 < TPB; ++t0) {
        const int k0 = (ks * TPB + t0) * KT;
        // stage K tile [d][k] AND V tile [k][d] together (8 indep loads/thread)
        for (int i = t; i < KT * 16; i += 256) {
            int a = i >> 4, c4 = (i & 15) * 4;
            *(float4*)(&kA[a][c4]) = *(const float4*)(kTbn + (size_t)a * SS + k0 + c4);
            *(float4*)(&vA[a][c4]) = *(const float4*)(vbn + (size_t)(k0 + a) * HD + c4);
        }
        __syncthreads();

        // QK from LDS
        float acc[2][4] = {};
#pragma unroll 16
        for (int d = 0; d < HD; ++d) {
            float2 q2 = *(const float2*)(&qsT[d][2 * qh]);
            float4 k4 = *(const float4*)(&kA[d][4 * kg]);
            acc[0][0] += q2.x * k4.x; acc[0][1] += q2.x * k4.y;
            acc[0][2] += q2.x * k4.z; acc[0][3] += q2.x * k4.w;
            acc[1][0] += q2.y * k4.x; acc[1][1] += q2.y * k4.y;
            acc[1][2] += q2.y * k4.z; acc[1][3] += q2.y * k4.w;
        }
#pragma unroll
        for (int e = 0; e < 2; ++e) {
            int qq = 2 * qh + e;
            int4 iv = *(const int4*)(ib + (size_t)(q0 + qq) * SS + k0 + 4 * kg);
            float p0 = __expf((acc[e][0] + qpkS[qq][iv.x]) * 0.125f);
            float p1 = __expf((acc[e][1] + qpkS[qq][iv.y]) * 0.125f);
            float p2 = __expf((acc[e][2] + qpkS[qq][iv.z]) * 0.125f);
            float p3 = __expf((acc[e][3] + qpkS[qq][iv.w]) * 0.125f);
            float4 pv4; pv4.x = p0; pv4.y = p1; pv4.z = p2; pv4.w = p3;
            *(float4*)(&attQ[qq][4 * kg]) = pv4;
            if (iv.x < KCLIP) atomicAdd(&wbuf[qq][iv.x], p0);
            if (iv.y < KCLIP) atomicAdd(&wbuf[qq][iv.y], p1);
            if (iv.z < KCLIP) atomicAdd(&wbuf[qq][iv.z], p2);
            if (iv.w < KCLIP) atomicAdd(&wbuf[qq][iv.w], p3);
            psum[e] += p0 + p1 + p2 + p3;
        }
        // NO barrier: attQ rows 2qh,2qh+1 produced & consumed by this wave

        // PV from LDS
#pragma unroll 8
        for (int kk = 0; kk < KT; kk += 2) {
            float2 a0 = *(const float2*)(&attQ[2 * qh][kk]);
            float2 a1 = *(const float2*)(&attQ[2 * qh + 1][kk]);
            float4 v0 = *(const float4*)(&vA[kk][4 * kg]);
            float4 v1 = *(const float4*)(&vA[kk + 1][4 * kg]);
            out1[0][0] += a0.x * v0.x; out1[0][1] += a0.x * v0.y;
            out1[0][2] += a0.x * v0.z; out1[0][3] += a0.x * v0.w;
            out1[1][0] += a1.x * v0.x; out1[1][1] += a1.x * v0.y;
            out1[1][2] += a1.x * v0.z; out1[1][3] += a1.x * v0.w;
            out1[0][0] += a0.y * v1.x; out1[0][1] += a0.y * v1.y;
            out1[0][2] += a0.y * v1.z; out1[0][3] += a0.y * v1.w;
            out1[1][0] += a1.y * v1.x; out1[1][1] += a1.y * v1.y;
            out1[1][2] += a1.y * v1.z; out1[1][3] += a1.y * v1.w;
        }
        __syncthreads();   // all waves done with kA/vA before next staging
    }

#pragma unroll
    for (int off = 8; off; off >>= 1) {
        psum[0] += __shfl_xor(psum[0], off);
        psum[1] += __shfl_xor(psum[1], off);
    }
    const size_t rbase = (size_t)ks * NROW + (size_t)bn * SS + q0;
    if (kg == 0) {
        pspart[rbase + 2 * qh] = psum[0];
        pspart[rbase + 2 * qh + 1] = psum[1];
    }
#pragma unroll
    for (int e = 0; e < 2; ++e) {
        int qq = 2 * qh + e;
        *(float4*)(o1p + (rbase + qq) * HD + 4 * kg) = *(float4*)(out1[e]);
    }
    __syncthreads();   // wbuf copy-out crosses waves
    for (int i = t; i < TQ * KCLIP / 4; i += 256) {
        int r = i >> 4, c4 = (i & 15) * 4;
        *(float4*)(wbpart + (rbase + r) * KCLIP + c4) = *(const float4*)(&wbuf[r][c4]);
    }
}

// ---------------------------------------------------------------------------
// K3b: combine partials -> heads. (unchanged)
// ---------------------------------------------------------------------------
__global__ __launch_bounds__(256) void attn_combine_kernel(
    const float* __restrict__ o1p, const float* __restrict__ pspart,
    const float* __restrict__ wbpart, const float* __restrict__ pe_v,
    float* __restrict__ heads)
{
    __shared__ float wl[4][66];
    const int t = threadIdx.x;
    const int rt = t >> 6, d = t & 63;
    const int row = blockIdx.x * 4 + rt;
    const int bn = row / SS, qq = row % SS;
    const int b = bn >> 3, n = bn & 7;

    float w = 0.f, rsum = 0.f, o = 0.f;
#pragma unroll
    for (int ks = 0; ks < KS; ++ks) {
        w += wbpart[((size_t)ks * NROW + row) * KCLIP + d];
        rsum += pspart[(size_t)ks * NROW + row];
        o += o1p[((size_t)ks * NROW + row) * HD + d];
    }
    wl[rt][d] = w;
    __syncthreads();

    const float pv64 = pe_v[KCLIP * HD + d];
    float acc = o;
#pragma unroll 8
    for (int c = 0; c < KCLIP; ++c)
        acc += wl[rt][c] * (pe_v[c * HD + d] - pv64);
    heads[((size_t)b * SS + qq) * HIDD + n * HD + d] = acc / rsum + pv64;
}

// ---------------------------------------------------------------------------
// K5: fc: out = heads @ fc_W^T + fc_b. (unchanged)
// ---------------------------------------------------------------------------
__global__ __launch_bounds__(256) void fc_kernel(
    const float* __restrict__ heads, const float* __restrict__ fcW,
    const float* __restrict__ fcb, float* __restrict__ out)
{
    const int m0 = blockIdx.x * 32;
    const int n0 = blockIdx.y * 64;

    __shared__ float As[32][36];
    __shared__ float Bs[32][64];

    const int t = threadIdx.x;
    const int ty = t >> 4;
    const int tx = t & 15;

    float acc[2][4] = {};
    for (int k0 = 0; k0 < HIDD; k0 += 32) {
        {
            int row = t >> 3, kc = (t & 7) * 4;
            float4 a4 = *(const float4*)(heads + (size_t)(m0 + row) * HIDD + k0 + kc);
            As[kc + 0][row] = a4.x; As[kc + 1][row] = a4.y;
            As[kc + 2][row] = a4.z; As[kc + 3][row] = a4.w;
        }
#pragma unroll
        for (int u = 0; u < 2; ++u) {
            int i = t + u * 256;
            int nl = i >> 3, kl = (i & 7) * 4;
            float4 bw = *(const float4*)(fcW + (size_t)(n0 + nl) * HIDD + k0 + kl);
            Bs[kl + 0][nl] = bw.x; Bs[kl + 1][nl] = bw.y;
            Bs[kl + 2][nl] = bw.z; Bs[kl + 3][nl] = bw.w;
        }
        __syncthreads();
#pragma unroll
        for (int kk = 0; kk < 32; ++kk) {
            float a0 = As[kk][2 * ty];
            float a1 = As[kk][2 * ty + 1];
            float4 b4 = *(const float4*)(&Bs[kk][4 * tx]);
            acc[0][0] += a0 * b4.x; acc[0][1] += a0 * b4.y;
            acc[0][2] += a0 * b4.z; acc[0][3] += a0 * b4.w;
            acc[1][0] += a1 * b4.x; acc[1][1] += a1 * b4.y;
            acc[1][2] += a1 * b4.z; acc[1][3] += a1 * b4.w;
        }
        __syncthreads();
    }
    float4 bb = *(const float4*)(fcb + n0 + 4 * tx);
#pragma unroll
    for (int e = 0; e < 2; ++e) {
        float4 r4;
        r4.x = acc[e][0] + bb.x; r4.y = acc[e][1] + bb.y;
        r4.z = acc[e][2] + bb.z; r4.w = acc[e][3] + bb.w;
        *(float4*)(out + (size_t)(m0 + 2 * ty + e) * HIDD + n0 + 4 * tx) = r4;
    }
}

// ---------------------------------------------------------------------------
extern "C" void kernel_launch(void* const* d_in, const int* in_sizes, int n_in,
                              void* d_out, int out_size, void* d_ws, size_t ws_size,
                              hipStream_t stream)
{
    (void)in_sizes; (void)n_in; (void)out_size; (void)ws_size;
    const float* query  = (const float*)d_in[0];
    const float* key_   = (const float*)d_in[1];
    const float* value  = (const float*)d_in[2];
    const float* coords = (const float*)d_in[3];
    const float* Wq = (const float*)d_in[4];
    const float* bq = (const float*)d_in[5];
    const float* Wk = (const float*)d_in[6];
    const float* bk = (const float*)d_in[7];
    const float* Wv = (const float*)d_in[8];
    const float* bv = (const float*)d_in[9];
    const float* pe_k = (const float*)d_in[10];
    const float* pe_v = (const float*)d_in[11];
    const float* fcW  = (const float*)d_in[12];
    const float* fcb  = (const float*)d_in[13];
    float* out = (float*)d_out;

    char* ws = (char*)d_ws;
    size_t off = 0;
    auto alloc = [&](size_t bytes) -> void* {
        void* p = ws + off;
        off += (bytes + 255) & ~(size_t)255;
        return p;
    };
    int*   idx    = (int*)  alloc((size_t)BB * SS * SS * sizeof(int));       // 4.7 MB
    float* qb     = (float*)alloc((size_t)NPROJ * sizeof(float));            // 3 MB
    float* kTb    = (float*)alloc((size_t)NPROJ * sizeof(float));            // 3 MB
    float* vb     = (float*)alloc((size_t)NPROJ * sizeof(float));            // 3 MB
    float* headb  = (float*)alloc((size_t)BB * SS * HIDD * sizeof(float));   // 3 MB
    float* qpkg   = (float*)alloc((size_t)NROW * QPAD * sizeof(float));      // 3.3 MB

    // union region: proj partials (37.7 MB) alias the attention partials
    // (o1p 12.6 + pspart 0.2 + wbpart 12.6 = 25.4 MB). proj partials are
    // fully consumed by proj_combine before attn_part writes o1p/ps/wb.
    const size_t o1p_b = (size_t)KS * NROW * HD * sizeof(float);
    const size_t ps_b  = ((size_t)KS * NROW * sizeof(float) + 255) & ~(size_t)255;
    const size_t pp_b  = (size_t)3 * 4 * MM * HIDD * sizeof(float);
    char* uni = (char*)alloc(pp_b);
    float* ppart  = (float*)uni;
    float* o1p    = (float*)uni;
    float* pspart = (float*)(uni + ((o1p_b + 255) & ~(size_t)255));
    float* wbpart = (float*)(uni + ((o1p_b + 255) & ~(size_t)255) + ps_b);

    idx_fill_kernel<<<(BB * SS * SS) / (256 * 4), 256, 0, stream>>>(idx);

    rel_idx_kernel<<<BB * LCO, 256, 0, stream>>>(coords, idx);

    proj_part_kernel<<<dim3(MM / 64, NH, 12), 256, 0, stream>>>(
        query, key_, value, Wq, Wk, Wv, ppart);

    proj_combine_kernel<<<dim3(MM / 64, NH, 3), 256, 0, stream>>>(
        ppart, bq, bk, bv, qb, kTb, vb);

    qpk_kernel<<<dim3(SS / 16, BB * NH), 256, 0, stream>>>(qb, pe_k, qpkg);

    attn_part_kernel<<<dim3(SS / TQ, BB * NH, KS), 256, 0, stream>>>(
        qb, kTb, vb, idx, qpkg, o1p, pspart, wbpart);

    attn_combine_kernel<<<NROW / 4, 256, 0, stream>>>(o1p, pspart, wbpart, pe_v, headb);

    fc_kernel<<<dim3(MM / 32, HIDD / 64), 256, 0, stream>>>(headb, fcW, fcb, out);
}